// Round 9
// baseline (258.661 us; speedup 1.0000x reference)
//
#include <hip/hip_runtime.h>
#include <math.h>

typedef __attribute__((ext_vector_type(8))) short short8;
typedef __attribute__((ext_vector_type(4))) float f32x4;
typedef __attribute__((ext_vector_type(8))) unsigned short u16x8;

#define TAUF 32.0f
#define SB() __builtin_amdgcn_sched_barrier(0)
#define BAR() __builtin_amdgcn_s_barrier()

constexpr int B_LO_OFF = 12288;  // lo plane offset within a buffer
constexpr int BUF_SZ   = 24576;  // one B buffer: 192 cols x 32 k x 2 planes
constexpr int CSTR     = 196;    // epilogue C row stride (floats)

// ---------------------------------------------------------------------------
// Kernel 1: PR rows = memory[dm].W as split-bf16 planes [192][768].
// ---------------------------------------------------------------------------
__global__ __launch_bounds__(768) void precompute_pr(
    const float* __restrict__ Wt, const float* __restrict__ Wd,
    const float* __restrict__ mem, unsigned short* __restrict__ PRhi,
    unsigned short* __restrict__ PRlo) {
  int r0 = blockIdx.x * 6, t = threadIdx.x;
  if (r0 >= 180) {
    #pragma unroll
    for (int rr = 0; rr < 6; ++rr) {
      PRhi[(size_t)(r0 + rr) * 768 + t] = 0;
      PRlo[(size_t)(r0 + rr) * 768 + t] = 0;
    }
    return;
  }
  __shared__ float mlds[1536];
  const float* W = (r0 >= 90) ? Wd : Wt;
  int dm0 = (r0 >= 90) ? r0 - 90 : r0;
  for (int i = t; i < 1536; i += 768) mlds[i] = mem[(size_t)dm0 * 256 + i];
  __syncthreads();
  float a[6] = {0.f, 0.f, 0.f, 0.f, 0.f, 0.f};
  #pragma unroll 4
  for (int e = 0; e < 256; ++e) {
    float w = W[(size_t)e * 768 + t];
    #pragma unroll
    for (int rr = 0; rr < 6; ++rr) a[rr] += mlds[rr * 256 + e] * w;
  }
  #pragma unroll
  for (int rr = 0; rr < 6; ++rr) {
    unsigned int bu = __float_as_uint(a[rr]);
    unsigned short hi = (unsigned short)(bu >> 16);
    float hf = __uint_as_float(bu & 0xffff0000u);
    unsigned short lo = (unsigned short)(__float_as_uint(a[rr] - hf) >> 16);
    PRhi[(size_t)(r0 + rr) * 768 + t] = hi;
    PRlo[(size_t)(r0 + rr) * 768 + t] = lo;
  }
}

// ---------------------------------------------------------------------------
// Kernel 2 (REAL, 8 waves): fused split-bf16 MFMA GEMM [64 x 192 x 768] +
// row L2-norm + double softmax. 512 threads = 8 waves (4 rg x 2 cg); wave
// owns 16 rows x 96 cols (18 MFMA/ktile). 16 waves/CU = 4/SIMD.
// ---------------------------------------------------------------------------
__global__ __launch_bounds__(512, 4) void fused_mfma(
    const float* __restrict__ feat, const unsigned short* __restrict__ PRhi,
    const unsigned short* __restrict__ PRlo, float* __restrict__ out) {
  __shared__ f32x4 smemv[3136];    // 50176 B: 2x24576 dbuf; C tile overlays
  __shared__ float invn[64];
  __shared__ float sarr[576];
  char* smem = (char*)smemv;

  const int t    = threadIdx.x;
  const int lane = t & 63;
  const int wid  = t >> 6;         // 0..7
  const int rg   = wid >> 1;       // 0..3: rows rg*16..+15
  const int cg   = wid & 1;        // cols cg*96..+95
  const int b0   = blockIdx.x * 64;

  // A frag source: lane -> row (lane&15), k-chunk (lane>>4)*8 floats
  const float* gA = feat + (size_t)(b0 + rg * 16 + (lane & 15)) * 768 +
                    ((lane >> 4) << 3);

  // B DMA: 24 instrs/ktile over 8 waves = 3/wave
  const int iid  = wid * 3;
  const int bc   = lane >> 2;
  const int bsw  = (lane & 3) ^ ((bc >> 1) & 3);
  const int bsrc = bc * 1536 + bsw * 16;

  // B fragment read offset (swizzled, conflict-free)
  const int bfr = ((lane & 15) << 6) |
                  ((((lane >> 4) ^ (((lane & 15) >> 1) & 3)) & 3) << 4);

  f32x4 acc[6];
  #pragma unroll
  for (int j = 0; j < 6; ++j) acc[j] = (f32x4){0.f, 0.f, 0.f, 0.f};
  float ssq = 0.f;

  auto issueB = [&](int kt, int bb) {
    #pragma unroll
    for (int u = 0; u < 3; ++u) {
      int i  = iid + u;
      int pl = i >= 12;
      int ch = pl ? i - 12 : i;
      const unsigned short* basep = pl ? PRlo : PRhi;
      const char* gg = (const char*)basep + (size_t)ch * 16 * 1536 +
                       kt * 64 + bsrc;
      char* l = smem + bb * BUF_SZ + (pl ? B_LO_OFF : 0) + ch * 1024 +
                lane * 16;
      __builtin_amdgcn_global_load_lds((const unsigned int*)gg,
                                       (unsigned int*)l, 16, 0, 0);
    }
  };

  float4 Aa0, Aa1, Ab0, Ab1;
  auto loadAa = [&](int kt) {
    Aa0 = *(const float4*)(gA + kt * 32);
    Aa1 = *(const float4*)(gA + kt * 32 + 4);
  };
  auto loadAb = [&](int kt) {
    Ab0 = *(const float4*)(gA + kt * 32);
    Ab1 = *(const float4*)(gA + kt * 32 + 4);
  };

  short8 ah, al;
  auto cvtCore = [&](float4 ra, float4 rb) {
    float xs[8] = {ra.x, ra.y, ra.z, ra.w, rb.x, rb.y, rb.z, rb.w};
    u16x8 h, l;
    #pragma unroll
    for (int e = 0; e < 8; ++e) {
      float x = xs[e];
      ssq += x * x;
      unsigned int bu = __float_as_uint(x);
      h[e] = (unsigned short)(bu >> 16);
      l[e] = (unsigned short)(__float_as_uint(
                 x - __uint_as_float(bu & 0xffff0000u)) >> 16);
    }
    ah = (short8)h;
    al = (short8)l;
  };

  auto domfma = [&](int bb) {
    char* base = smem + bb * BUF_SZ;
    #pragma unroll
    for (int j = 0; j < 6; ++j) {
      int chb = (cg * 6 + j) * 1024;
      short8 bh = *(const short8*)(base + chb + bfr);
      short8 bl = *(const short8*)(base + B_LO_OFF + chb + bfr);
      acc[j] = __builtin_amdgcn_mfma_f32_16x16x32_bf16(ah, bh, acc[j], 0, 0, 0);
      acc[j] = __builtin_amdgcn_mfma_f32_16x16x32_bf16(al, bh, acc[j], 0, 0, 0);
      acc[j] = __builtin_amdgcn_mfma_f32_16x16x32_bf16(ah, bl, acc[j], 0, 0, 0);
    }
  };

  // prologue: queue order B0,A0,B1,A1 (10 deep); drain B0 only
  issueB(0, 0);
  loadAa(0);
  issueB(1, 1);
  loadAb(1);
  asm volatile("s_waitcnt vmcnt(7)" ::: "memory");
  SB(); BAR();

  for (int kp = 0; kp < 11; ++kp) {
    int kt = 2 * kp;
    cvtCore(Aa0, Aa1);
    domfma(0);
    SB(); BAR();
    issueB(kt + 2, 0);
    loadAa(kt + 2);
    asm volatile("s_waitcnt vmcnt(7)" ::: "memory");  // B(kt+1) landed
    SB(); BAR();
    cvtCore(Ab0, Ab1);
    domfma(1);
    SB(); BAR();
    issueB(kt + 3, 1);
    loadAb(kt + 3);
    asm volatile("s_waitcnt vmcnt(7)" ::: "memory");  // B(kt+2) landed
    SB(); BAR();
  }
  // tail: kt=22 (buf0), kt=23 (buf1, B23+A23 already in flight)
  cvtCore(Aa0, Aa1);
  domfma(0);
  SB(); BAR();
  asm volatile("s_waitcnt vmcnt(2)" ::: "memory");    // B(23) landed
  SB(); BAR();
  cvtCore(Ab0, Ab1);
  domfma(1);

  // ---- row L2-norm: lanes l, l+16, l+32, l+48 hold 4 k-chunk partials
  float v = ssq;
  v += __shfl_xor(v, 16, 64);
  v += __shfl_xor(v, 32, 64);
  if (cg == 0 && lane < 16) invn[rg * 16 + lane] = rsqrtf(v);
  __syncthreads();

  // ---- write scaled C (q|r) to LDS
  float* Clds = (float*)smem;
  {
    int rbase = rg * 16 + ((lane >> 4) << 2);
    float iv[4];
    #pragma unroll
    for (int jj = 0; jj < 4; ++jj) iv[jj] = invn[rbase + jj];
    #pragma unroll
    for (int j = 0; j < 6; ++j) {
      int col = cg * 96 + j * 16 + (lane & 15);
      #pragma unroll
      for (int jj = 0; jj < 4; ++jj)
        Clds[(rbase + jj) * CSTR + col] = acc[j][jj] * iv[jj];
    }
  }
  __syncthreads();

  // ---- per (row,d): softmax over m, dot with r
  for (int pid = t; pid < 576; pid += 512) {
    int row = pid / 9, d = pid - row * 9;
    const float* qp = Clds + row * CSTR + d * 10;
    const float* rp = qp + 90;
    float mx = qp[0];
    #pragma unroll
    for (int m = 1; m < 10; ++m) mx = fmaxf(mx, qp[m]);
    float s = 0.f, val = 0.f;
    #pragma unroll
    for (int m = 0; m < 10; ++m) {
      float e = __expf(TAUF * (qp[m] - mx));
      s += e;
      val += e * rp[m];
    }
    sarr[pid] = val / s;
  }
  __syncthreads();

  // ---- per row: softmax over d, write out
  if (t < 64) {
    float v2[9];
    #pragma unroll
    for (int d = 0; d < 9; ++d) v2[d] = sarr[t * 9 + d];
    float mx = v2[0];
    #pragma unroll
    for (int d = 1; d < 9; ++d) mx = fmaxf(mx, v2[d]);
    float s = 0.f;
    float e[9];
    #pragma unroll
    for (int d = 0; d < 9; ++d) {
      e[d] = __expf(TAUF * (v2[d] - mx));
      s += e[d];
    }
    float is = 1.f / s;
    #pragma unroll
    for (int d = 0; d < 9; ++d)
      out[(size_t)(b0 + t) * 9 + d] = e[d] * is;
  }
}

// ---------------------------------------------------------------------------
// ABLATION: the DMA+vmcnt+2-barrier skeleton ONLY, repeated x10 (240 ktiles)
// so it stays visible above the top-5 cutoff. No A-loads, no cvt, no MFMA,
// no ds_read. Unit cost = dispatch_time / 10.
// ---------------------------------------------------------------------------
__global__ __launch_bounds__(512, 4) void abl_dma10(
    const unsigned short* __restrict__ PRhi,
    const unsigned short* __restrict__ PRlo) {
  __shared__ f32x4 smemv[3072];   // 49152: 2 B-buffers
  char* smem = (char*)smemv;
  const int lane = threadIdx.x & 63;
  const int wid  = threadIdx.x >> 6;
  const int iid  = wid * 3;
  const int bc   = lane >> 2;
  const int bsw  = (lane & 3) ^ ((bc >> 1) & 3);
  const int bsrc = bc * 1536 + bsw * 16;

  auto issueB = [&](int kt, int bb) {
    #pragma unroll
    for (int u = 0; u < 3; ++u) {
      int i  = iid + u;
      int pl = i >= 12;
      int ch = pl ? i - 12 : i;
      const unsigned short* basep = pl ? PRlo : PRhi;
      const char* gg = (const char*)basep + (size_t)ch * 16 * 1536 +
                       kt * 64 + bsrc;
      char* l = smem + bb * BUF_SZ + (pl ? B_LO_OFF : 0) + ch * 1024 +
                lane * 16;
      __builtin_amdgcn_global_load_lds((const unsigned int*)gg,
                                       (unsigned int*)l, 16, 0, 0);
    }
  };

  issueB(0, 0);
  issueB(1, 1);
  asm volatile("s_waitcnt vmcnt(3)" ::: "memory");
  SB(); BAR();
  int kt = 2;
  for (int it = 0; it < 238; ++it) {
    SB(); BAR();                 // mirrors the post-compute barrier
    issueB(kt, it & 1);
    asm volatile("s_waitcnt vmcnt(3)" ::: "memory");
    SB(); BAR();
    kt = (kt == 23) ? 0 : kt + 1;
  }
  asm volatile("s_waitcnt vmcnt(0)" ::: "memory");
  SB(); BAR();
}

extern "C" void kernel_launch(void* const* d_in, const int* in_sizes, int n_in,
                              void* d_out, int out_size, void* d_ws, size_t ws_size,
                              hipStream_t stream) {
  const float* feat = (const float*)d_in[0];
  // d_in[1] = category (unused by forward math)
  const float* Wt  = (const float*)d_in[2];
  const float* Wd  = (const float*)d_in[3];
  const float* mem = (const float*)d_in[4];
  float* outp = (float*)d_out;

  unsigned short* PRhi = (unsigned short*)d_ws;   // [192][768] bf16
  unsigned short* PRlo = PRhi + 192 * 768;        // [192][768] bf16

  precompute_pr<<<32, 768, 0, stream>>>(Wt, Wd, mem, PRhi, PRlo);
  const int B = in_sizes[1];   // 32768
  const int nblk = B / 64;     // 512
  fused_mfma<<<nblk, 512, 0, stream>>>(feat, PRhi, PRlo, outp);
  // attribution probe (timing only; writes nothing global)
  abl_dma10<<<nblk, 512, 0, stream>>>(PRhi, PRlo);
}

// Round 10
// 82.965 us; speedup vs baseline: 3.1177x; 3.1177x over previous
//
#include <hip/hip_runtime.h>
#include <math.h>

typedef __attribute__((ext_vector_type(8))) short short8;
typedef __attribute__((ext_vector_type(4))) float f32x4;
typedef __attribute__((ext_vector_type(8))) unsigned short u16x8;

#define TAUF 32.0f
#define SB() __builtin_amdgcn_sched_barrier(0)
#define BAR() __builtin_amdgcn_s_barrier()

constexpr int B_LO_OFF = 12288;  // lo plane offset within a buffer
constexpr int BUF_SZ   = 24576;  // one B buffer: 192 cols x 32 k x 2 planes
constexpr int CSTR     = 196;    // epilogue C row stride (floats)

// ---------------------------------------------------------------------------
// Kernel 1: PR rows = memory[dm].W as split-bf16 planes [192][768].
// ---------------------------------------------------------------------------
__global__ __launch_bounds__(768) void precompute_pr(
    const float* __restrict__ Wt, const float* __restrict__ Wd,
    const float* __restrict__ mem, unsigned short* __restrict__ PRhi,
    unsigned short* __restrict__ PRlo) {
  int r0 = blockIdx.x * 6, t = threadIdx.x;
  if (r0 >= 180) {
    #pragma unroll
    for (int rr = 0; rr < 6; ++rr) {
      PRhi[(size_t)(r0 + rr) * 768 + t] = 0;
      PRlo[(size_t)(r0 + rr) * 768 + t] = 0;
    }
    return;
  }
  __shared__ float mlds[1536];
  const float* W = (r0 >= 90) ? Wd : Wt;
  int dm0 = (r0 >= 90) ? r0 - 90 : r0;
  for (int i = t; i < 1536; i += 768) mlds[i] = mem[(size_t)dm0 * 256 + i];
  __syncthreads();
  float a[6] = {0.f, 0.f, 0.f, 0.f, 0.f, 0.f};
  #pragma unroll 4
  for (int e = 0; e < 256; ++e) {
    float w = W[(size_t)e * 768 + t];
    #pragma unroll
    for (int rr = 0; rr < 6; ++rr) a[rr] += mlds[rr * 256 + e] * w;
  }
  #pragma unroll
  for (int rr = 0; rr < 6; ++rr) {
    unsigned int bu = __float_as_uint(a[rr]);
    unsigned short hi = (unsigned short)(bu >> 16);
    float hf = __uint_as_float(bu & 0xffff0000u);
    unsigned short lo = (unsigned short)(__float_as_uint(a[rr] - hf) >> 16);
    PRhi[(size_t)(r0 + rr) * 768 + t] = hi;
    PRlo[(size_t)(r0 + rr) * 768 + t] = lo;
  }
}

// ---------------------------------------------------------------------------
// Kernel 2: fused split-bf16 MFMA GEMM [128 rows x 192 cols x K=768] +
// row L2-norm + double softmax. 512 threads = 8 waves (4 rg x 2 cg); wave
// owns 32 rows (2 rowtiles) x 96 cols. Grid 256 = 1 block/CU: B L2-refetch
// amortized over 2x rows (B feed 430 cy << A HBM feed 1600 cy per ktile).
// Counted-vmcnt pipeline: B 1 tile ahead (dbuf), A 2 tiles ahead in regs.
// Epilogue in two 64-row phases reusing the dbuf LDS.
// ---------------------------------------------------------------------------
__global__ __launch_bounds__(512, 2) void fused_mfma(
    const float* __restrict__ feat, const unsigned short* __restrict__ PRhi,
    const unsigned short* __restrict__ PRlo, float* __restrict__ out) {
  __shared__ f32x4 smemv[3136];    // 50176 B: 2x24576 dbuf; C half-tile overlays
  __shared__ float invn[128];
  __shared__ float sarr[576];
  char* smem = (char*)smemv;

  const int t    = threadIdx.x;
  const int lane = t & 63;
  const int wid  = t >> 6;         // 0..7
  const int rg   = wid >> 1;       // 0..3: rows rg*32..+31
  const int cg   = wid & 1;        // cols cg*96..+95
  const int b0   = blockIdx.x * 128;

  // A frag source: lane -> row (lane&15), k-chunk (lane>>4)*8 floats
  const float* gA0 = feat + (size_t)(b0 + rg * 32 + (lane & 15)) * 768 +
                     ((lane >> 4) << 3);
  const float* gA1 = gA0 + 16 * 768;

  // B DMA: 24 instrs/ktile over 8 waves = 3/wave; XOR-granule source swizzle
  const int iid  = wid * 3;
  const int bc   = lane >> 2;
  const int bsw  = (lane & 3) ^ ((bc >> 1) & 3);
  const int bsrc = bc * 1536 + bsw * 16;

  // B fragment read offset (matching swizzle, conflict-free)
  const int bfr = ((lane & 15) << 6) |
                  ((((lane >> 4) ^ (((lane & 15) >> 1) & 3)) & 3) << 4);

  f32x4 acc0[6], acc1[6];
  #pragma unroll
  for (int j = 0; j < 6; ++j) {
    acc0[j] = (f32x4){0.f, 0.f, 0.f, 0.f};
    acc1[j] = (f32x4){0.f, 0.f, 0.f, 0.f};
  }
  float ssq0 = 0.f, ssq1 = 0.f;

  auto issueB = [&](int kt, int bb) {
    #pragma unroll
    for (int u = 0; u < 3; ++u) {
      int i  = iid + u;
      int pl = i >= 12;
      int ch = pl ? i - 12 : i;
      const unsigned short* basep = pl ? PRlo : PRhi;
      const char* gg = (const char*)basep + (size_t)ch * 16 * 1536 +
                       kt * 64 + bsrc;
      char* l = smem + bb * BUF_SZ + (pl ? B_LO_OFF : 0) + ch * 1024 +
                lane * 16;
      __builtin_amdgcn_global_load_lds((const unsigned int*)gg,
                                       (unsigned int*)l, 16, 0, 0);
    }
  };

  float4 Aa0, Aa1, Aa2, Aa3, Ab0, Ab1, Ab2, Ab3;
  auto loadAa = [&](int kt) {
    Aa0 = *(const float4*)(gA0 + kt * 32);
    Aa1 = *(const float4*)(gA0 + kt * 32 + 4);
    Aa2 = *(const float4*)(gA1 + kt * 32);
    Aa3 = *(const float4*)(gA1 + kt * 32 + 4);
  };
  auto loadAb = [&](int kt) {
    Ab0 = *(const float4*)(gA0 + kt * 32);
    Ab1 = *(const float4*)(gA0 + kt * 32 + 4);
    Ab2 = *(const float4*)(gA1 + kt * 32);
    Ab3 = *(const float4*)(gA1 + kt * 32 + 4);
  };

  short8 ah0, al0, ah1, al1;
  auto cvtCore = [&](float4 ra0a, float4 ra0b, float4 ra1a, float4 ra1b) {
    float x0[8] = {ra0a.x, ra0a.y, ra0a.z, ra0a.w,
                   ra0b.x, ra0b.y, ra0b.z, ra0b.w};
    float x1[8] = {ra1a.x, ra1a.y, ra1a.z, ra1a.w,
                   ra1b.x, ra1b.y, ra1b.z, ra1b.w};
    u16x8 h0, l0, h1, l1;
    #pragma unroll
    for (int e = 0; e < 8; ++e) {
      float x = x0[e];
      ssq0 += x * x;
      unsigned int bu = __float_as_uint(x);
      h0[e] = (unsigned short)(bu >> 16);
      l0[e] = (unsigned short)(__float_as_uint(
                  x - __uint_as_float(bu & 0xffff0000u)) >> 16);
      float y = x1[e];
      ssq1 += y * y;
      unsigned int bv = __float_as_uint(y);
      h1[e] = (unsigned short)(bv >> 16);
      l1[e] = (unsigned short)(__float_as_uint(
                  y - __uint_as_float(bv & 0xffff0000u)) >> 16);
    }
    ah0 = (short8)h0; al0 = (short8)l0; ah1 = (short8)h1; al1 = (short8)l1;
  };

  auto domfma = [&](int bb) {
    char* base = smem + bb * BUF_SZ;
    #pragma unroll
    for (int j = 0; j < 6; ++j) {
      int chb = (cg * 6 + j) * 1024;
      short8 bh = *(const short8*)(base + chb + bfr);
      short8 bl = *(const short8*)(base + B_LO_OFF + chb + bfr);
      acc0[j] = __builtin_amdgcn_mfma_f32_16x16x32_bf16(ah0, bh, acc0[j], 0, 0, 0);
      acc0[j] = __builtin_amdgcn_mfma_f32_16x16x32_bf16(al0, bh, acc0[j], 0, 0, 0);
      acc0[j] = __builtin_amdgcn_mfma_f32_16x16x32_bf16(ah0, bl, acc0[j], 0, 0, 0);
      acc1[j] = __builtin_amdgcn_mfma_f32_16x16x32_bf16(ah1, bh, acc1[j], 0, 0, 0);
      acc1[j] = __builtin_amdgcn_mfma_f32_16x16x32_bf16(al1, bh, acc1[j], 0, 0, 0);
      acc1[j] = __builtin_amdgcn_mfma_f32_16x16x32_bf16(ah1, bl, acc1[j], 0, 0, 0);
    }
  };

  // prologue: B0->buf0, A0->a, B1->buf1, A1->b (14 outstanding); drain B0
  issueB(0, 0);
  loadAa(0);
  issueB(1, 1);
  loadAb(1);
  asm volatile("s_waitcnt vmcnt(11)" ::: "memory");
  SB(); BAR();

  for (int kp = 0; kp < 11; ++kp) {
    int kt = 2 * kp;
    cvtCore(Aa0, Aa1, Aa2, Aa3);
    domfma(0);
    SB(); BAR();
    issueB(kt + 2, 0);
    loadAa(kt + 2);
    asm volatile("s_waitcnt vmcnt(11)" ::: "memory");  // B(kt+1) landed
    SB(); BAR();
    cvtCore(Ab0, Ab1, Ab2, Ab3);
    domfma(1);
    SB(); BAR();
    issueB(kt + 3, 1);
    loadAb(kt + 3);
    asm volatile("s_waitcnt vmcnt(11)" ::: "memory");  // B(kt+2) landed
    SB(); BAR();
  }
  // tail: kt=22 (buf0), then kt=23 (buf1; B23+A23 already in flight)
  cvtCore(Aa0, Aa1, Aa2, Aa3);
  domfma(0);
  SB(); BAR();
  asm volatile("s_waitcnt vmcnt(4)" ::: "memory");     // B(23) landed
  SB(); BAR();
  cvtCore(Ab0, Ab1, Ab2, Ab3);
  domfma(1);

  // ---- row L2-norm: lanes l, l+16, l+32, l+48 hold the 4 k-chunk partials
  float v0 = ssq0, v1 = ssq1;
  v0 += __shfl_xor(v0, 16, 64); v0 += __shfl_xor(v0, 32, 64);
  v1 += __shfl_xor(v1, 16, 64); v1 += __shfl_xor(v1, 32, 64);
  if (cg == 0 && lane < 16) {
    invn[rg * 32 + lane]      = rsqrtf(v0);
    invn[rg * 32 + 16 + lane] = rsqrtf(v1);
  }
  __syncthreads();   // all MFMA reads drained; invn visible; smem reusable

  // ---- epilogue in two 64-row phases (C half-tile reuses dbuf LDS)
  float* Clds = (float*)smem;
  for (int ph = 0; ph < 2; ++ph) {
    if ((rg >> 1) == ph) {       // waves rg=2ph,2ph+1 own these 64 rows
      int lrow = (rg & 1) * 32;  // local row base within the half-tile
      #pragma unroll
      for (int rt = 0; rt < 2; ++rt) {
        int rbase = lrow + rt * 16 + ((lane >> 4) << 2);
        int grow  = ph * 64 + rbase;       // global (block) row for invn
        #pragma unroll
        for (int j = 0; j < 6; ++j) {
          int col = cg * 96 + j * 16 + (lane & 15);
          f32x4 v = rt ? acc1[j] : acc0[j];
          #pragma unroll
          for (int jj = 0; jj < 4; ++jj)
            Clds[(rbase + jj) * CSTR + col] = v[jj] * invn[grow + jj];
        }
      }
    }
    __syncthreads();

    // per (row,d): softmax over m, dot with r   (rows = ph*64 .. +63)
    for (int pid = t; pid < 576; pid += 512) {
      int row = pid / 9, d = pid - row * 9;
      const float* qp = Clds + row * CSTR + d * 10;
      const float* rp = qp + 90;
      float mx = qp[0];
      #pragma unroll
      for (int m = 1; m < 10; ++m) mx = fmaxf(mx, qp[m]);
      float s = 0.f, val = 0.f;
      #pragma unroll
      for (int m = 0; m < 10; ++m) {
        float e = __expf(TAUF * (qp[m] - mx));
        s += e;
        val += e * rp[m];
      }
      sarr[pid] = val / s;
    }
    __syncthreads();

    // per row: softmax over d, write out
    if (t < 64) {
      float v2[9];
      #pragma unroll
      for (int d = 0; d < 9; ++d) v2[d] = sarr[t * 9 + d];
      float mx = v2[0];
      #pragma unroll
      for (int d = 1; d < 9; ++d) mx = fmaxf(mx, v2[d]);
      float s = 0.f;
      float e[9];
      #pragma unroll
      for (int d = 0; d < 9; ++d) {
        e[d] = __expf(TAUF * (v2[d] - mx));
        s += e[d];
      }
      float is = 1.f / s;
      #pragma unroll
      for (int d = 0; d < 9; ++d)
        out[(size_t)(b0 + ph * 64 + t) * 9 + d] = e[d] * is;
    }
    __syncthreads();   // phase-1 sarr readers done before phase-2 overwrites
  }
}

extern "C" void kernel_launch(void* const* d_in, const int* in_sizes, int n_in,
                              void* d_out, int out_size, void* d_ws, size_t ws_size,
                              hipStream_t stream) {
  const float* feat = (const float*)d_in[0];
  // d_in[1] = category (unused by forward math)
  const float* Wt  = (const float*)d_in[2];
  const float* Wd  = (const float*)d_in[3];
  const float* mem = (const float*)d_in[4];
  float* outp = (float*)d_out;

  unsigned short* PRhi = (unsigned short*)d_ws;   // [192][768] bf16
  unsigned short* PRlo = PRhi + 192 * 768;        // [192][768] bf16

  precompute_pr<<<32, 768, 0, stream>>>(Wt, Wd, mem, PRhi, PRlo);
  const int B = in_sizes[1];   // 32768
  fused_mfma<<<B / 128, 512, 0, stream>>>(feat, PRhi, PRlo, outp);
}

// Round 11
// 71.068 us; speedup vs baseline: 3.6396x; 1.1674x over previous
//
#include <hip/hip_runtime.h>
#include <math.h>

typedef __attribute__((ext_vector_type(8))) short short8;
typedef __attribute__((ext_vector_type(4))) float f32x4;
typedef __attribute__((ext_vector_type(8))) unsigned short u16x8;

#define TAUF 32.0f
#define SB() __builtin_amdgcn_sched_barrier(0)
#define BAR() __builtin_amdgcn_s_barrier()

// LDS layout: [A buf0 16K][A buf1 16K][B buf0 24K][B buf1 24K] = 81920 B
constexpr int A_SZ     = 16384;  // 128 rows x 32 k x 4B
constexpr int B_BASE   = 32768;
constexpr int B_LO_OFF = 12288;
constexpr int B_SZ     = 24576;
constexpr int CSTR     = 196;    // epilogue C row stride (floats)

// ---------------------------------------------------------------------------
// Kernel 1: PR rows = memory[dm].W as split-bf16 planes [192][768].
// ---------------------------------------------------------------------------
__global__ __launch_bounds__(768) void precompute_pr(
    const float* __restrict__ Wt, const float* __restrict__ Wd,
    const float* __restrict__ mem, unsigned short* __restrict__ PRhi,
    unsigned short* __restrict__ PRlo) {
  int r0 = blockIdx.x * 6, t = threadIdx.x;
  if (r0 >= 180) {
    #pragma unroll
    for (int rr = 0; rr < 6; ++rr) {
      PRhi[(size_t)(r0 + rr) * 768 + t] = 0;
      PRlo[(size_t)(r0 + rr) * 768 + t] = 0;
    }
    return;
  }
  __shared__ float mlds[1536];
  const float* W = (r0 >= 90) ? Wd : Wt;
  int dm0 = (r0 >= 90) ? r0 - 90 : r0;
  for (int i = t; i < 1536; i += 768) mlds[i] = mem[(size_t)dm0 * 256 + i];
  __syncthreads();
  float a[6] = {0.f, 0.f, 0.f, 0.f, 0.f, 0.f};
  #pragma unroll 4
  for (int e = 0; e < 256; ++e) {
    float w = W[(size_t)e * 768 + t];
    #pragma unroll
    for (int rr = 0; rr < 6; ++rr) a[rr] += mlds[rr * 256 + e] * w;
  }
  #pragma unroll
  for (int rr = 0; rr < 6; ++rr) {
    unsigned int bu = __float_as_uint(a[rr]);
    unsigned short hi = (unsigned short)(bu >> 16);
    float hf = __uint_as_float(bu & 0xffff0000u);
    unsigned short lo = (unsigned short)(__float_as_uint(a[rr] - hf) >> 16);
    PRhi[(size_t)(r0 + rr) * 768 + t] = hi;
    PRlo[(size_t)(r0 + rr) * 768 + t] = lo;
  }
}

// ---------------------------------------------------------------------------
// Kernel 2: fused split-bf16 MFMA GEMM [128 x 192 x 768] + L2-norm + double
// softmax. 512 threads = 8 waves (4 rg x 2 cg); wave owns 32 rows x 96 cols.
// A: f32 tile staged to LDS via global_load_lds with DENSE source lines
// (8 lanes/row x 16B consecutive) and XOR-granule swizzle (source-side);
// fragments ds_read with matching swizzle (~2-way, free). B: as R4 (dense,
// swizzled). 5 vmem/wave/ktile, counted vmcnt(5), dbuf, 2 barriers/ktile.
// ---------------------------------------------------------------------------
__global__ __launch_bounds__(512) void fused_mfma(
    const float* __restrict__ feat, const unsigned short* __restrict__ PRhi,
    const unsigned short* __restrict__ PRlo, float* __restrict__ out) {
  __shared__ f32x4 smemv[5120];    // 81920 B; C half-tile (50176 B) overlays
  __shared__ float invn[128];
  __shared__ float sarr[576];
  char* smem = (char*)smemv;

  const int t    = threadIdx.x;
  const int lane = t & 63;
  const int wid  = t >> 6;         // 0..7
  const int rg   = wid >> 1;       // 0..3: rows rg*32..+31
  const int cg   = wid & 1;        // cols cg*96..+95
  const int b0   = blockIdx.x * 128;

  // ---- A staging: 16 instrs/ktile (2/wave). Granule G = (wid*2+u)*64+lane:
  // row = G>>3 (8 granules of 16B per 128B row), physical slot = G&7 holds
  // logical k-granule (G&7)^(row&7). Source: dense 128B per row.
  const char* featB = (const char*)feat;

  auto issueA = [&](int kt, int bb) {
    #pragma unroll
    for (int u = 0; u < 2; ++u) {
      int G   = (wid * 2 + u) * 64 + lane;
      int row = G >> 3;
      int kq  = (G & 7) ^ (row & 7);
      const char* src = featB + (size_t)(b0 + row) * 3072 + kt * 128 + kq * 16;
      char* dst = smem + bb * A_SZ + G * 16;
      __builtin_amdgcn_global_load_lds((const unsigned int*)src,
                                       (unsigned int*)dst, 16, 0, 0);
    }
  };

  // ---- B DMA: 24 instrs/ktile (3/wave), XOR-granule source swizzle (R4)
  const int iid  = wid * 3;
  const int bc   = lane >> 2;
  const int bsw  = (lane & 3) ^ ((bc >> 1) & 3);
  const int bsrc = bc * 1536 + bsw * 16;

  auto issueB = [&](int kt, int bb) {
    #pragma unroll
    for (int u = 0; u < 3; ++u) {
      int i  = iid + u;
      int pl = i >= 12;
      int ch = pl ? i - 12 : i;
      const unsigned short* basep = pl ? PRlo : PRhi;
      const char* gg = (const char*)basep + (size_t)ch * 16 * 1536 +
                       kt * 64 + bsrc;
      char* l = smem + B_BASE + bb * B_SZ + (pl ? B_LO_OFF : 0) + ch * 1024 +
                lane * 16;
      __builtin_amdgcn_global_load_lds((const unsigned int*)gg,
                                       (unsigned int*)l, 16, 0, 0);
    }
  };

  // ---- B fragment read offset (matching swizzle, conflict-free)
  const int bfr = ((lane & 15) << 6) |
                  ((((lane >> 4) ^ (((lane & 15) >> 1) & 3)) & 3) << 4);

  f32x4 acc0[6], acc1[6];
  #pragma unroll
  for (int j = 0; j < 6; ++j) {
    acc0[j] = (f32x4){0.f, 0.f, 0.f, 0.f};
    acc1[j] = (f32x4){0.f, 0.f, 0.f, 0.f};
  }
  float ssq0 = 0.f, ssq1 = 0.f;

  short8 ah0, al0, ah1, al1;

  // read A fragments from LDS (swizzled) + cvt to split-bf16, fold ssq
  auto readA = [&](int bb) {
    char* base = smem + bb * A_SZ;
    const int c = lane >> 4;
    #pragma unroll
    for (int rt = 0; rt < 2; ++rt) {
      int row = rg * 32 + rt * 16 + (lane & 15);
      int p0  = (2 * c)     ^ (row & 7);
      int p1  = (2 * c + 1) ^ (row & 7);
      f32x4 v0 = *(const f32x4*)(base + row * 128 + p0 * 16);
      f32x4 v1 = *(const f32x4*)(base + row * 128 + p1 * 16);
      float xs[8] = {v0[0], v0[1], v0[2], v0[3], v1[0], v1[1], v1[2], v1[3]};
      u16x8 h, l;
      float ss = 0.f;
      #pragma unroll
      for (int e = 0; e < 8; ++e) {
        float x = xs[e];
        ss += x * x;
        unsigned int bu = __float_as_uint(x);
        h[e] = (unsigned short)(bu >> 16);
        l[e] = (unsigned short)(__float_as_uint(
                   x - __uint_as_float(bu & 0xffff0000u)) >> 16);
      }
      if (rt == 0) { ah0 = (short8)h; al0 = (short8)l; ssq0 += ss; }
      else         { ah1 = (short8)h; al1 = (short8)l; ssq1 += ss; }
    }
  };

  auto domfma = [&](int bb) {
    char* base = smem + B_BASE + bb * B_SZ;
    #pragma unroll
    for (int j = 0; j < 6; ++j) {
      int chb = (cg * 6 + j) * 1024;
      short8 bh = *(const short8*)(base + chb + bfr);
      short8 bl = *(const short8*)(base + B_LO_OFF + chb + bfr);
      acc0[j] = __builtin_amdgcn_mfma_f32_16x16x32_bf16(ah0, bh, acc0[j], 0, 0, 0);
      acc0[j] = __builtin_amdgcn_mfma_f32_16x16x32_bf16(al0, bh, acc0[j], 0, 0, 0);
      acc0[j] = __builtin_amdgcn_mfma_f32_16x16x32_bf16(ah0, bl, acc0[j], 0, 0, 0);
      acc1[j] = __builtin_amdgcn_mfma_f32_16x16x32_bf16(ah1, bh, acc1[j], 0, 0, 0);
      acc1[j] = __builtin_amdgcn_mfma_f32_16x16x32_bf16(al1, bh, acc1[j], 0, 0, 0);
      acc1[j] = __builtin_amdgcn_mfma_f32_16x16x32_bf16(ah1, bl, acc1[j], 0, 0, 0);
    }
  };

  // ---- prologue: stage kt=0 and kt=1 (5 vmem/wave each); drain kt=0
  issueA(0, 0); issueB(0, 0);
  issueA(1, 1); issueB(1, 1);
  asm volatile("s_waitcnt vmcnt(5)" ::: "memory");
  SB(); BAR();

  // ---- main loop: 2 ktiles/iter (compile-time buffer parity)
  for (int kp = 0; kp < 11; ++kp) {
    int kt = 2 * kp;
    readA(0);
    domfma(0);
    SB(); BAR();                 // all reads of buf0 done
    issueA(kt + 2, 0); issueB(kt + 2, 0);
    asm volatile("s_waitcnt vmcnt(5)" ::: "memory");   // kt+1 landed
    SB(); BAR();
    readA(1);
    domfma(1);
    SB(); BAR();                 // all reads of buf1 done
    issueA(kt + 3, 1); issueB(kt + 3, 1);
    asm volatile("s_waitcnt vmcnt(5)" ::: "memory");   // kt+2 landed
    SB(); BAR();
  }
  // tail: kt=22 (buf0), kt=23 (buf1, already in flight)
  readA(0);
  domfma(0);
  SB(); BAR();
  asm volatile("s_waitcnt vmcnt(0)" ::: "memory");     // kt=23 landed
  SB(); BAR();
  readA(1);
  domfma(1);

  // ---- row L2-norm: lanes l, l+16, l+32, l+48 hold the 4 k-chunk partials
  float v0 = ssq0, v1 = ssq1;
  v0 += __shfl_xor(v0, 16, 64); v0 += __shfl_xor(v0, 32, 64);
  v1 += __shfl_xor(v1, 16, 64); v1 += __shfl_xor(v1, 32, 64);
  if (cg == 0 && lane < 16) {
    invn[rg * 32 + lane]      = rsqrtf(v0);
    invn[rg * 32 + 16 + lane] = rsqrtf(v1);
  }
  __syncthreads();   // all LDS reads drained; invn visible; smem reusable

  // ---- epilogue in two 64-row phases (C half-tile reuses staging LDS)
  float* Clds = (float*)smem;
  for (int ph = 0; ph < 2; ++ph) {
    if ((rg >> 1) == ph) {       // waves rg=2ph,2ph+1 own these 64 rows
      int lrow = (rg & 1) * 32;
      #pragma unroll
      for (int rt = 0; rt < 2; ++rt) {
        int rbase = lrow + rt * 16 + ((lane >> 4) << 2);
        int grow  = ph * 64 + rbase;
        #pragma unroll
        for (int j = 0; j < 6; ++j) {
          int col = cg * 96 + j * 16 + (lane & 15);
          f32x4 v = rt ? acc1[j] : acc0[j];
          #pragma unroll
          for (int jj = 0; jj < 4; ++jj)
            Clds[(rbase + jj) * CSTR + col] = v[jj] * invn[grow + jj];
        }
      }
    }
    __syncthreads();

    for (int pid = t; pid < 576; pid += 512) {
      int row = pid / 9, d = pid - row * 9;
      const float* qp = Clds + row * CSTR + d * 10;
      const float* rp = qp + 90;
      float mx = qp[0];
      #pragma unroll
      for (int m = 1; m < 10; ++m) mx = fmaxf(mx, qp[m]);
      float s = 0.f, val = 0.f;
      #pragma unroll
      for (int m = 0; m < 10; ++m) {
        float e = __expf(TAUF * (qp[m] - mx));
        s += e;
        val += e * rp[m];
      }
      sarr[pid] = val / s;
    }
    __syncthreads();

    if (t < 64) {
      float v2[9];
      #pragma unroll
      for (int d = 0; d < 9; ++d) v2[d] = sarr[t * 9 + d];
      float mx = v2[0];
      #pragma unroll
      for (int d = 1; d < 9; ++d) mx = fmaxf(mx, v2[d]);
      float s = 0.f;
      float e[9];
      #pragma unroll
      for (int d = 0; d < 9; ++d) {
        e[d] = __expf(TAUF * (v2[d] - mx));
        s += e[d];
      }
      float is = 1.f / s;
      #pragma unroll
      for (int d = 0; d < 9; ++d)
        out[(size_t)(b0 + ph * 64 + t) * 9 + d] = e[d] * is;
    }
    __syncthreads();
  }
}

extern "C" void kernel_launch(void* const* d_in, const int* in_sizes, int n_in,
                              void* d_out, int out_size, void* d_ws, size_t ws_size,
                              hipStream_t stream) {
  const float* feat = (const float*)d_in[0];
  // d_in[1] = category (unused by forward math)
  const float* Wt  = (const float*)d_in[2];
  const float* Wd  = (const float*)d_in[3];
  const float* mem = (const float*)d_in[4];
  float* outp = (float*)d_out;

  unsigned short* PRhi = (unsigned short*)d_ws;   // [192][768] bf16
  unsigned short* PRlo = PRhi + 192 * 768;        // [192][768] bf16

  precompute_pr<<<32, 768, 0, stream>>>(Wt, Wd, mem, PRhi, PRlo);
  const int B = in_sizes[1];   // 32768
  fused_mfma<<<B / 128, 512, 0, stream>>>(feat, PRhi, PRlo, outp);
}